// Round 9
// baseline (301.766 us; speedup 1.0000x reference)
//
#include <hip/hip_runtime.h>

// Problem constants
#define S_LEN 2048
#define NH    16
#define DH    64
#define DM    1024
#define NQKV  3072

typedef __attribute__((ext_vector_type(8))) __bf16 bf16x8;
typedef __attribute__((ext_vector_type(4))) float  f32x4;
typedef unsigned short ushort_t;

static __device__ __forceinline__ unsigned short bf16b(float f) {
  return __builtin_bit_cast(unsigned short, (__bf16)f);
}

static __device__ __forceinline__ float exp2v(float x) {
  return __builtin_amdgcn_exp2f(x);   // v_exp_f32: D = 2^S0
}

static __device__ __forceinline__ bf16x8 pack8(float4 f0, float4 f1) {
  uint4 v;
  v.x = ((unsigned)bf16b(f0.y) << 16) | bf16b(f0.x);
  v.y = ((unsigned)bf16b(f0.w) << 16) | bf16b(f0.z);
  v.z = ((unsigned)bf16b(f1.y) << 16) | bf16b(f1.x);
  v.w = ((unsigned)bf16b(f1.w) << 16) | bf16b(f1.z);
  return __builtin_bit_cast(bf16x8, v);
}

static __device__ __forceinline__ void glds16(const void* g, void* l) {
  __builtin_amdgcn_global_load_lds((const __attribute__((address_space(1))) unsigned int*)g,
                                   (__attribute__((address_space(3))) unsigned int*)l, 16, 0, 0);
}

// ---------------- workspace layout (bytes) ----------------
#define OFF_WT  65536ull      // 3072*1024*2 (dead after gemm_qkv -> reused as l_buf)
#define OFF_LB  65536ull      // l_buf: 32*2048 fp32 = 256 KB (aliases dead Wt)
#define OFF_WOT 6356992ull    // 1024*1024*2
#define OFF_Q   8454144ull
#define OFF_K   16842752ull
#define OFF_V   25231360ull
#define OFF_AO  33619968ull   // xb before attn, AO (bf16) after normalize

// ---------------- fused prep: fold (MFMA) | transpose | castx ----------------
__global__ __launch_bounds__(256) void k_prep(const float* __restrict__ wqkv,
                                              const float* __restrict__ wout,
                                              const float* __restrict__ x,
                                              const float* __restrict__ logits,
                                              unsigned short* __restrict__ Wt,
                                              unsigned short* __restrict__ Wot,
                                              unsigned short* __restrict__ xb) {
  __shared__ __align__(16) char sbuf[16640];
  int bid = blockIdx.x;
  int t = threadIdx.x;

  if (bid < 256) {
    float* msk = (float*)sbuf;
    float* Kd  = (float*)(sbuf + 144);
    ushort_t (*Fb)[72] = (ushort_t(*)[72])(sbuf + 416);
    if (t < 33) msk[t] = 1.0f / (1.0f + __expf(-logits[t]));
    __syncthreads();
    if (t < 64) {
      float acc = msk[0];
      #pragma unroll
      for (int f = 1; f < 32; ++f) {
        int r = (f * t) & 63;
        acc += 2.0f * msk[f] * __cosf((float)r * (6.28318530717958647692f / 64.0f));
      }
      acc += msk[32] * ((t & 1) ? -1.0f : 1.0f);
      Kd[t] = acc * (1.0f / 64.0f);
    }
    __syncthreads();
    for (int idx = t; idx < 4096; idx += 256) {
      int j = idx >> 6, i = idx & 63;
      Fb[j][i] = bf16b(Kd[(j - i) & 63]);
    }
    __syncthreads();

    int lane = t & 63, w = t >> 6;
    int m16 = lane & 15, quad = lane >> 4;
    int kx = bid >> 5, yy = bid & 31;
    int which = yy >> 4, h = yy & 15;
    int base = which * 1024 + h * 64;

    bf16x8 af0 = *(const bf16x8*)(&Fb[w * 16 + m16][quad * 8]);
    bf16x8 af1 = *(const bf16x8*)(&Fb[w * 16 + m16][32 + quad * 8]);

    f32x4 acc[8] = {};
    #pragma unroll 2
    for (int n = 0; n < 8; ++n) {
      const float* Wg = wqkv + (size_t)(kx * 128 + n * 16 + m16) * NQKV + base + quad * 8;
      float4 a0 = *(const float4*)(Wg);
      float4 a1 = *(const float4*)(Wg + 4);
      float4 b0 = *(const float4*)(Wg + 32);
      float4 b1 = *(const float4*)(Wg + 36);
      acc[n] = __builtin_amdgcn_mfma_f32_16x16x32_bf16(af0, pack8(a0, a1), acc[n], 0, 0, 0);
      acc[n] = __builtin_amdgcn_mfma_f32_16x16x32_bf16(af1, pack8(b0, b1), acc[n], 0, 0, 0);
    }
    float sc = (which == 0) ? 0.18033688011112042f : 1.0f;   // 0.125 * log2(e) into q
    #pragma unroll
    for (int n = 0; n < 8; ++n) {
      #pragma unroll
      for (int r = 0; r < 4; ++r) {
        int j = w * 16 + quad * 4 + r;
        Wt[(size_t)(base + j) * DM + kx * 128 + n * 16 + m16] = bf16b(acc[n][r] * sc);
      }
    }
  } else if (bid < 768) {
    float (*Ts)[65] = (float(*)[65])sbuf;
    int b1 = bid - 256;
    if (b1 < 256) {
      int kt = b1 & 15, nt = b1 >> 4;
      int cb = 2048 + nt * 64, kbase = kt * 64;
      #pragma unroll
      for (int p = 0; p < 16; ++p) {
        int kk = p * 4 + (t >> 6);
        Ts[kk][t & 63] = wqkv[(size_t)(kbase + kk) * NQKV + cb + (t & 63)];
      }
      __syncthreads();
      #pragma unroll
      for (int p = 0; p < 16; ++p) {
        int nn = p * 4 + (t >> 6);
        Wt[(size_t)(cb + nn) * DM + kbase + (t & 63)] = bf16b(Ts[t & 63][nn]);
      }
    } else {
      int b2 = b1 - 256;
      int kt = b2 & 15, nt = b2 >> 4;
      int cb = nt * 64, kbase = kt * 64;
      #pragma unroll
      for (int p = 0; p < 16; ++p) {
        int kk = p * 4 + (t >> 6);
        Ts[kk][t & 63] = wout[(size_t)(kbase + kk) * DM + cb + (t & 63)];
      }
      __syncthreads();
      #pragma unroll
      for (int p = 0; p < 16; ++p) {
        int nn = p * 4 + (t >> 6);
        Wot[(size_t)(cb + nn) * DM + kbase + (t & 63)] = bf16b(Ts[t & 63][nn]);
      }
    }
  } else {
    size_t i = ((size_t)(bid - 768) * 256 + t) * 8;
    const float4* xp = (const float4*)(x + i);
    float4 a = xp[0], b = xp[1];
    uint4 v;
    v.x = ((unsigned)bf16b(a.y) << 16) | bf16b(a.x);
    v.y = ((unsigned)bf16b(a.w) << 16) | bf16b(a.z);
    v.z = ((unsigned)bf16b(b.y) << 16) | bf16b(b.x);
    v.w = ((unsigned)bf16b(b.w) << 16) | bf16b(b.z);
    *(uint4*)(xb + i) = v;
  }
}

// ---------------- 128x128-tile GEMM core, m97-style: global_load_lds + XOR swizzle ----------------
__device__ __forceinline__ void gemm_core_async(const unsigned short* __restrict__ A,
                                                const unsigned short* __restrict__ Bw,
                                                int bm, int bn, unsigned short* smem,
                                                f32x4 (&acc)[4][4]) {
  unsigned short* As = smem;
  unsigned short* Bs = smem + 8192;
  int t = threadIdx.x, lane = t & 63, w = t >> 6;
  int m16 = lane & 15, quad = lane >> 4;
  int wr = (w >> 1) * 64, wc = (w & 1) * 64;
  int lr = lane >> 3, lc = lane & 7;
  int gc = lc ^ lr;
  int xr = m16 & 7;
  const unsigned short* Agb = A  + (size_t)(bm * 128) * DM + gc * 8;
  const unsigned short* Bgb = Bw + (size_t)(bn * 128) * DM + gc * 8;

  for (int k0 = 0; k0 < DM; k0 += 64) {
    #pragma unroll
    for (int p = 0; p < 4; ++p) {
      int row = p * 32 + w * 8 + lr;
      glds16(Agb + (size_t)row * DM + k0, As + row * 64 + lc * 8);
      glds16(Bgb + (size_t)row * DM + k0, Bs + row * 64 + lc * 8);
    }
    __syncthreads();
    #pragma unroll
    for (int kk = 0; kk < 2; ++kk) {
      bf16x8 af[4], bfr[4];
      #pragma unroll
      for (int i = 0; i < 4; ++i)
        af[i] = *(const bf16x8*)(As + (wr + i * 16 + m16) * 64 + ((kk * 4 + quad) ^ xr) * 8);
      #pragma unroll
      for (int j = 0; j < 4; ++j)
        bfr[j] = *(const bf16x8*)(Bs + (wc + j * 16 + m16) * 64 + ((kk * 4 + quad) ^ xr) * 8);
      #pragma unroll
      for (int i = 0; i < 4; ++i)
        #pragma unroll
        for (int j = 0; j < 4; ++j)
          acc[i][j] = __builtin_amdgcn_mfma_f32_16x16x32_bf16(af[i], bfr[j], acc[i][j], 0, 0, 0);
    }
    __syncthreads();
  }
}

// ---------------- GEMM1: qkv = xb @ Wt^T, scatter Q,K (bhsd) and V^T (bhds) ----------------
__global__ __launch_bounds__(256) void k_gemm_qkv(const unsigned short* __restrict__ xb,
                                                  const unsigned short* __restrict__ Bw,
                                                  unsigned short* __restrict__ Qb,
                                                  unsigned short* __restrict__ Kb,
                                                  unsigned short* __restrict__ Vt) {
  __shared__ __align__(16) unsigned short smem[18432];
  f32x4 acc[4][4] = {};
  int bn = blockIdx.x, bm = blockIdx.y;
  gemm_core_async(xb, Bw, bm, bn, smem, acc);

  int t = threadIdx.x, lane = t & 63, w = t >> 6;
  int m16 = lane & 15, quad = lane >> 4;
  int wr = (w >> 1) * 64, wc = (w & 1) * 64;
  int b = bm >> 4, srow = (bm & 15) * 128;
  int which = bn >> 3;
  ushort_t (*Tr)[130] = (ushort_t(*)[130])smem;
  if (which < 2) {
    #pragma unroll
    for (int i = 0; i < 4; ++i)
      #pragma unroll
      for (int j = 0; j < 4; ++j)
        #pragma unroll
        for (int r = 0; r < 4; ++r)
          Tr[wr + i * 16 + quad * 4 + r][wc + j * 16 + m16] = bf16b(acc[i][j][r]);
    __syncthreads();
    int row = t >> 1, half = t & 1;
    int cloc = bn * 128 + half * 64 - which * 1024;
    int h = cloc >> 6;
    unsigned short* dst = (which ? Kb : Qb) +
        ((size_t)(b * 16 + h) * 2048 + srow + row) * 64;
    #pragma unroll
    for (int p = 0; p < 8; ++p)
      *(uint4*)(dst + p * 8) = *(const uint4*)(&Tr[row][half * 64 + p * 8]);
  } else {
    #pragma unroll
    for (int i = 0; i < 4; ++i)
      #pragma unroll
      for (int j = 0; j < 4; ++j)
        #pragma unroll
        for (int r = 0; r < 4; ++r)
          Tr[wc + j * 16 + m16][wr + i * 16 + quad * 4 + r] = bf16b(acc[i][j][r]);
    __syncthreads();
    int dl = t >> 1, half = t & 1;
    int cloc = (bn - 16) * 128 + dl;
    int h = cloc >> 6, d = cloc & 63;
    unsigned short* dst = Vt + ((size_t)(b * 16 + h) * 64 + d) * 2048 + srow + half * 64;
    #pragma unroll
    for (int p = 0; p < 8; ++p)
      *(uint4*)(dst + p * 8) = *(const uint4*)(&Tr[dl][half * 64 + p * 8]);
  }
}

// ---------------- flash attention v3: 32q/wave, K in LDS dbuf, V in regs, 2-way key split ----------------
// grid 1024: xcd = bid&7, bh = ((bid>>3)&3)*8 + xcd, rest = bid>>5: ks = rest&1, qtile = rest>>1.
// 256 threads = 4 waves; wave owns 32 q rows; 16 iterations of 64 keys over its key half.
// Unnormalized fp32 o -> atomicAdd into dout (zeroed); l -> atomicAdd l_buf.
// LDS: K dbuf 2*64*64 = 8192 sh + P 4*32*68 = 8704 sh -> 16896 sh = 33792 B
// (R8 bug: declared 16704 -> wave-3 P overran the allocation; intermittent corruption.)
__global__ __launch_bounds__(256, 4) void k_attn(const unsigned short* __restrict__ Qb,
                                                 const unsigned short* __restrict__ Kb,
                                                 const unsigned short* __restrict__ Vt,
                                                 float* __restrict__ dout,
                                                 float* __restrict__ l_buf) {
  __shared__ __align__(16) unsigned short smem[16896];   // 33792 B; 4 blocks/CU = 132 KB < 160 KB
  int t = threadIdx.x;
  int w = t >> 6, lane = t & 63;
  int m16 = lane & 15, quad = lane >> 4;
  int bid = blockIdx.x;
  int bh = (((bid >> 3) & 3) << 3) + (bid & 7);
  int rest = bid >> 5;
  int ks = rest & 1, qtile = rest >> 1;
  int qbase = qtile * 128 + w * 32;
  int kbase0 = ks * 1024;

  const unsigned short* Qp = Qb + ((size_t)bh * S_LEN + qbase + m16) * DH + quad * 8;
  bf16x8 aq00 = *(const bf16x8*)(Qp);
  bf16x8 aq01 = *(const bf16x8*)(Qp + 32);
  bf16x8 aq10 = *(const bf16x8*)(Qp + 16 * DH);
  bf16x8 aq11 = *(const bf16x8*)(Qp + 16 * DH + 32);
  const unsigned short* Kbase = Kb + (size_t)bh * S_LEN * DH + (size_t)kbase0 * DH;
  const unsigned short* Vbase = Vt + (size_t)bh * DH * S_LEN + kbase0;

  unsigned short* Pw = smem + 8192 + w * 2176;   // 32 x 68
  int xr = m16 & 7;

  int trow = t >> 3;            // 0..31
  int tcol = t & 7;
  int gswz = tcol ^ (trow & 7);

  f32x4 o0[4] = {}, o1[4] = {};
  float l0 = 0.f, l1 = 0.f;
  f32x4 zero = {0.f, 0.f, 0.f, 0.f};

  // stage K tile 0 into buf 0 (two 32-row chunks per thread)
  glds16(Kbase + (size_t)trow * 64 + gswz * 8,        smem + trow * 64 + tcol * 8);
  glds16(Kbase + (size_t)(trow + 32) * 64 + gswz * 8, smem + (trow + 32) * 64 + tcol * 8);
  __syncthreads();

  #pragma unroll 1
  for (int kt = 0; kt < 16; ++kt) {
    int cur = kt & 1, nxt = cur ^ 1;
    int k0 = kt * 64;
    // V fragments for this tile -> registers (L2 latency covered by QK+softmax below)
    bf16x8 vf[2][4];
    #pragma unroll
    for (int c = 0; c < 2; ++c)
      #pragma unroll
      for (int j = 0; j < 4; ++j)
        vf[c][j] = *(const bf16x8*)(Vbase + (size_t)(j * 16 + m16) * S_LEN + k0 + c * 32 + quad * 8);
    // stage next K tile
    if (kt < 15) {
      int kk = k0 + 64;
      glds16(Kbase + (size_t)(kk + trow) * 64 + gswz * 8,
             smem + nxt * 4096 + trow * 64 + tcol * 8);
      glds16(Kbase + (size_t)(kk + trow + 32) * 64 + gswz * 8,
             smem + nxt * 4096 + (trow + 32) * 64 + tcol * 8);
    }
    unsigned short* Ksh = smem + cur * 4096;

    // QK^T transposed (st rows = keys, col = q); K frags shared by both q-halves
    f32x4 st0[4], st1[4];
    #pragma unroll
    for (int g = 0; g < 4; ++g) {
      int rk = g * 16 + m16;
      bf16x8 kf0 = *(const bf16x8*)(Ksh + rk * 64 + ((quad ^ xr) * 8));
      bf16x8 kf1 = *(const bf16x8*)(Ksh + rk * 64 + (((4 + quad) ^ xr) * 8));
      st0[g] = __builtin_amdgcn_mfma_f32_16x16x32_bf16(kf0, aq00, zero, 0, 0, 0);
      st0[g] = __builtin_amdgcn_mfma_f32_16x16x32_bf16(kf1, aq01, st0[g], 0, 0, 0);
      st1[g] = __builtin_amdgcn_mfma_f32_16x16x32_bf16(kf0, aq10, zero, 0, 0, 0);
      st1[g] = __builtin_amdgcn_mfma_f32_16x16x32_bf16(kf1, aq11, st1[g], 0, 0, 0);
    }
    // softmax: p = 2^s
    #pragma unroll
    for (int g = 0; g < 4; ++g) {
      float p0 = exp2v(st0[g][0]), p1 = exp2v(st0[g][1]);
      float p2 = exp2v(st0[g][2]), p3 = exp2v(st0[g][3]);
      l0 += (p0 + p1) + (p2 + p3);
      uint2 pk;
      pk.x = ((unsigned)bf16b(p1) << 16) | bf16b(p0);
      pk.y = ((unsigned)bf16b(p3) << 16) | bf16b(p2);
      *(uint2*)(Pw + m16 * 68 + g * 16 + quad * 4) = pk;
    }
    #pragma unroll
    for (int g = 0; g < 4; ++g) {
      float p0 = exp2v(st1[g][0]), p1 = exp2v(st1[g][1]);
      float p2 = exp2v(st1[g][2]), p3 = exp2v(st1[g][3]);
      l1 += (p0 + p1) + (p2 + p3);
      uint2 pk;
      pk.x = ((unsigned)bf16b(p1) << 16) | bf16b(p0);
      pk.y = ((unsigned)bf16b(p3) << 16) | bf16b(p2);
      *(uint2*)(Pw + (16 + m16) * 68 + g * 16 + quad * 4) = pk;
    }
    // PV: o(32q x 64d) += P(32x64) @ V^T
    #pragma unroll
    for (int c = 0; c < 2; ++c) {
      bf16x8 ap0 = *(const bf16x8*)(Pw + m16 * 68 + c * 32 + quad * 8);
      bf16x8 ap1 = *(const bf16x8*)(Pw + (16 + m16) * 68 + c * 32 + quad * 8);
      #pragma unroll
      for (int j = 0; j < 4; ++j) {
        o0[j] = __builtin_amdgcn_mfma_f32_16x16x32_bf16(ap0, vf[c][j], o0[j], 0, 0, 0);
        o1[j] = __builtin_amdgcn_mfma_f32_16x16x32_bf16(ap1, vf[c][j], o1[j], 0, 0, 0);
      }
    }
    __syncthreads();   // K dbuf guard
  }

  // merge: unnormalized partials, linearly combinable across the 2 key-split blocks
  l0 += __shfl_xor(l0, 16); l0 += __shfl_xor(l0, 32);
  l1 += __shfl_xor(l1, 16); l1 += __shfl_xor(l1, 32);
  int b = bh >> 4, h = bh & 15;
  if (quad == 0) {
    atomicAdd(&l_buf[(size_t)bh * S_LEN + qbase + m16], l0);
    atomicAdd(&l_buf[(size_t)bh * S_LEN + qbase + 16 + m16], l1);
  }
  #pragma unroll
  for (int r = 0; r < 4; ++r) {
    size_t row0 = (size_t)b * S_LEN + qbase + quad * 4 + r;
    float* d0 = dout + row0 * DM + h * DH + m16;
    float* d1 = d0 + (size_t)16 * DM;
    #pragma unroll
    for (int j = 0; j < 4; ++j) {
      atomicAdd(d0 + j * 16, o0[j][r]);
      atomicAdd(d1 + j * 16, o1[j][r]);
    }
  }
}

// ---------------- normalize: AO_bf16 = dout * (1/l) ----------------
__global__ __launch_bounds__(256) void k_norm(const float* __restrict__ dout,
                                              const float* __restrict__ l_buf,
                                              unsigned short* __restrict__ AO) {
  size_t idx = ((size_t)blockIdx.x * 256 + threadIdx.x) * 8;
  int row = (int)(idx >> 10);
  int c = (int)(idx & 1023);
  int b = row >> 11, q = row & 2047, h = c >> 6;
  float inv = 1.0f / l_buf[(size_t)(b * 16 + h) * S_LEN + q];
  const float4* sp = (const float4*)(dout + idx);
  float4 a = sp[0], bb = sp[1];
  a.x *= inv; a.y *= inv; a.z *= inv; a.w *= inv;
  bb.x *= inv; bb.y *= inv; bb.z *= inv; bb.w *= inv;
  uint4 v;
  v.x = ((unsigned)bf16b(a.y) << 16) | bf16b(a.x);
  v.y = ((unsigned)bf16b(a.w) << 16) | bf16b(a.z);
  v.z = ((unsigned)bf16b(bb.y) << 16) | bf16b(bb.x);
  v.w = ((unsigned)bf16b(bb.w) << 16) | bf16b(bb.z);
  *(uint4*)(AO + idx) = v;
}

// ---------------- GEMM2: out = AO @ Wot^T + bias (fp32 out), grid (8, 32) ----------------
__global__ __launch_bounds__(256) void k_gemm_out(const unsigned short* __restrict__ A,
                                                  const unsigned short* __restrict__ Bw,
                                                  const float* __restrict__ bias,
                                                  float* __restrict__ out) {
  __shared__ __align__(16) unsigned short smem[18432];
  f32x4 acc[4][4] = {};
  int bn = blockIdx.x, bm = blockIdx.y;
  gemm_core_async(A, Bw, bm, bn, smem, acc);

  int t = threadIdx.x, lane = t & 63, w = t >> 6;
  int m16 = lane & 15, quad = lane >> 4;
  int wr = (w >> 1) * 64, wc = (w & 1) * 64;
  #pragma unroll
  for (int i = 0; i < 4; ++i) {
    int grow = bm * 128 + wr + i * 16 + quad * 4;
    #pragma unroll
    for (int j = 0; j < 4; ++j) {
      int gc = bn * 128 + wc + j * 16 + m16;
      float bb = bias[gc];
      #pragma unroll
      for (int r = 0; r < 4; ++r)
        out[(size_t)(grow + r) * DM + gc] = acc[i][j][r] + bb;
    }
  }
}

extern "C" void kernel_launch(void* const* d_in, const int* in_sizes, int n_in,
                              void* d_out, int out_size, void* d_ws, size_t ws_size,
                              hipStream_t stream) {
  const float* x    = (const float*)d_in[0];
  const float* wqkv = (const float*)d_in[1];
  const float* wout = (const float*)d_in[2];
  const float* bout = (const float*)d_in[3];
  const float* mlog = (const float*)d_in[4];
  char* ws = (char*)d_ws;
  unsigned short* Wt  = (unsigned short*)(ws + OFF_WT);
  float*          Lb  = (float*)(ws + OFF_LB);       // aliases Wt (dead after gemm_qkv)
  unsigned short* Wot = (unsigned short*)(ws + OFF_WOT);
  unsigned short* Qb  = (unsigned short*)(ws + OFF_Q);
  unsigned short* Kb  = (unsigned short*)(ws + OFF_K);
  unsigned short* Vt  = (unsigned short*)(ws + OFF_V);
  unsigned short* xb  = (unsigned short*)(ws + OFF_AO);
  unsigned short* AO  = (unsigned short*)(ws + OFF_AO);
  float* out = (float*)d_out;

  k_prep<<<dim3(2816), dim3(256), 0, stream>>>(wqkv, wout, x, mlog, Wt, Wot, xb);
  k_gemm_qkv<<<dim3(24, 32), dim3(256), 0, stream>>>(xb, Wt, Qb, Kb, Vt);
  hipMemsetAsync(out, 0, (size_t)4096 * 1024 * 4, stream);     // attn accumulates into d_out
  hipMemsetAsync(Lb, 0, (size_t)32 * 2048 * 4, stream);
  k_attn<<<dim3(1024), dim3(256), 0, stream>>>(Qb, Kb, Vt, out, Lb);
  k_norm<<<dim3(2048), dim3(256), 0, stream>>>(out, Lb, AO);
  k_gemm_out<<<dim3(8, 32), dim3(256), 0, stream>>>(AO, Wot, bout, out);
}

// Round 10
// 274.938 us; speedup vs baseline: 1.0976x; 1.0976x over previous
//
#include <hip/hip_runtime.h>

// Problem constants
#define S_LEN 2048
#define NH    16
#define DH    64
#define DM    1024
#define NQKV  3072

typedef __attribute__((ext_vector_type(8))) __bf16 bf16x8;
typedef __attribute__((ext_vector_type(4))) float  f32x4;
typedef unsigned short ushort_t;

static __device__ __forceinline__ unsigned short bf16b(float f) {
  return __builtin_bit_cast(unsigned short, (__bf16)f);
}

static __device__ __forceinline__ float exp2v(float x) {
  return __builtin_amdgcn_exp2f(x);   // v_exp_f32: D = 2^S0
}

static __device__ __forceinline__ bf16x8 pack8(float4 f0, float4 f1) {
  uint4 v;
  v.x = ((unsigned)bf16b(f0.y) << 16) | bf16b(f0.x);
  v.y = ((unsigned)bf16b(f0.w) << 16) | bf16b(f0.z);
  v.z = ((unsigned)bf16b(f1.y) << 16) | bf16b(f1.x);
  v.w = ((unsigned)bf16b(f1.w) << 16) | bf16b(f1.z);
  return __builtin_bit_cast(bf16x8, v);
}

static __device__ __forceinline__ void glds16(const void* g, void* l) {
  __builtin_amdgcn_global_load_lds((const __attribute__((address_space(1))) unsigned int*)g,
                                   (__attribute__((address_space(3))) unsigned int*)l, 16, 0, 0);
}

// ---------------- workspace layout (bytes) ----------------
#define OFF_WT  65536ull      // 3072*1024*2
#define OFF_WOT 6356992ull    // 1024*1024*2
#define OFF_Q   8454144ull
#define OFF_K   16842752ull
#define OFF_V   25231360ull
#define OFF_AO  33619968ull   // xb before attn, AO after

// ---------------- fused prep: fold (MFMA) | transpose | castx ----------------
__global__ __launch_bounds__(256) void k_prep(const float* __restrict__ wqkv,
                                              const float* __restrict__ wout,
                                              const float* __restrict__ x,
                                              const float* __restrict__ logits,
                                              unsigned short* __restrict__ Wt,
                                              unsigned short* __restrict__ Wot,
                                              unsigned short* __restrict__ xb) {
  __shared__ __align__(16) char sbuf[16640];
  int bid = blockIdx.x;
  int t = threadIdx.x;

  if (bid < 256) {
    float* msk = (float*)sbuf;
    float* Kd  = (float*)(sbuf + 144);
    ushort_t (*Fb)[72] = (ushort_t(*)[72])(sbuf + 416);
    if (t < 33) msk[t] = 1.0f / (1.0f + __expf(-logits[t]));
    __syncthreads();
    if (t < 64) {
      float acc = msk[0];
      #pragma unroll
      for (int f = 1; f < 32; ++f) {
        int r = (f * t) & 63;
        acc += 2.0f * msk[f] * __cosf((float)r * (6.28318530717958647692f / 64.0f));
      }
      acc += msk[32] * ((t & 1) ? -1.0f : 1.0f);
      Kd[t] = acc * (1.0f / 64.0f);
    }
    __syncthreads();
    for (int idx = t; idx < 4096; idx += 256) {
      int j = idx >> 6, i = idx & 63;
      Fb[j][i] = bf16b(Kd[(j - i) & 63]);
    }
    __syncthreads();

    int lane = t & 63, w = t >> 6;
    int m16 = lane & 15, quad = lane >> 4;
    int kx = bid >> 5, yy = bid & 31;
    int which = yy >> 4, h = yy & 15;
    int base = which * 1024 + h * 64;

    bf16x8 af0 = *(const bf16x8*)(&Fb[w * 16 + m16][quad * 8]);
    bf16x8 af1 = *(const bf16x8*)(&Fb[w * 16 + m16][32 + quad * 8]);

    f32x4 acc[8] = {};
    #pragma unroll 2
    for (int n = 0; n < 8; ++n) {
      const float* Wg = wqkv + (size_t)(kx * 128 + n * 16 + m16) * NQKV + base + quad * 8;
      float4 a0 = *(const float4*)(Wg);
      float4 a1 = *(const float4*)(Wg + 4);
      float4 b0 = *(const float4*)(Wg + 32);
      float4 b1 = *(const float4*)(Wg + 36);
      acc[n] = __builtin_amdgcn_mfma_f32_16x16x32_bf16(af0, pack8(a0, a1), acc[n], 0, 0, 0);
      acc[n] = __builtin_amdgcn_mfma_f32_16x16x32_bf16(af1, pack8(b0, b1), acc[n], 0, 0, 0);
    }
    float sc = (which == 0) ? 0.18033688011112042f : 1.0f;   // 0.125 * log2(e) into q
    #pragma unroll
    for (int n = 0; n < 8; ++n) {
      #pragma unroll
      for (int r = 0; r < 4; ++r) {
        int j = w * 16 + quad * 4 + r;
        Wt[(size_t)(base + j) * DM + kx * 128 + n * 16 + m16] = bf16b(acc[n][r] * sc);
      }
    }
  } else if (bid < 768) {
    float (*Ts)[65] = (float(*)[65])sbuf;
    int b1 = bid - 256;
    if (b1 < 256) {
      int kt = b1 & 15, nt = b1 >> 4;
      int cb = 2048 + nt * 64, kbase = kt * 64;
      #pragma unroll
      for (int p = 0; p < 16; ++p) {
        int kk = p * 4 + (t >> 6);
        Ts[kk][t & 63] = wqkv[(size_t)(kbase + kk) * NQKV + cb + (t & 63)];
      }
      __syncthreads();
      #pragma unroll
      for (int p = 0; p < 16; ++p) {
        int nn = p * 4 + (t >> 6);
        Wt[(size_t)(cb + nn) * DM + kbase + (t & 63)] = bf16b(Ts[t & 63][nn]);
      }
    } else {
      int b2 = b1 - 256;
      int kt = b2 & 15, nt = b2 >> 4;
      int cb = nt * 64, kbase = kt * 64;
      #pragma unroll
      for (int p = 0; p < 16; ++p) {
        int kk = p * 4 + (t >> 6);
        Ts[kk][t & 63] = wout[(size_t)(kbase + kk) * DM + cb + (t & 63)];
      }
      __syncthreads();
      #pragma unroll
      for (int p = 0; p < 16; ++p) {
        int nn = p * 4 + (t >> 6);
        Wot[(size_t)(cb + nn) * DM + kbase + (t & 63)] = bf16b(Ts[t & 63][nn]);
      }
    }
  } else {
    size_t i = ((size_t)(bid - 768) * 256 + t) * 8;
    const float4* xp = (const float4*)(x + i);
    float4 a = xp[0], b = xp[1];
    uint4 v;
    v.x = ((unsigned)bf16b(a.y) << 16) | bf16b(a.x);
    v.y = ((unsigned)bf16b(a.w) << 16) | bf16b(a.z);
    v.z = ((unsigned)bf16b(b.y) << 16) | bf16b(b.x);
    v.w = ((unsigned)bf16b(b.w) << 16) | bf16b(b.z);
    *(uint4*)(xb + i) = v;
  }
}

// ---------------- 128x128-tile GEMM core, m97-style: global_load_lds + XOR swizzle ----------------
__device__ __forceinline__ void gemm_core_async(const unsigned short* __restrict__ A,
                                                const unsigned short* __restrict__ Bw,
                                                int bm, int bn, unsigned short* smem,
                                                f32x4 (&acc)[4][4]) {
  unsigned short* As = smem;
  unsigned short* Bs = smem + 8192;
  int t = threadIdx.x, lane = t & 63, w = t >> 6;
  int m16 = lane & 15, quad = lane >> 4;
  int wr = (w >> 1) * 64, wc = (w & 1) * 64;
  int lr = lane >> 3, lc = lane & 7;
  int gc = lc ^ lr;
  int xr = m16 & 7;
  const unsigned short* Agb = A  + (size_t)(bm * 128) * DM + gc * 8;
  const unsigned short* Bgb = Bw + (size_t)(bn * 128) * DM + gc * 8;

  for (int k0 = 0; k0 < DM; k0 += 64) {
    #pragma unroll
    for (int p = 0; p < 4; ++p) {
      int row = p * 32 + w * 8 + lr;
      glds16(Agb + (size_t)row * DM + k0, As + row * 64 + lc * 8);
      glds16(Bgb + (size_t)row * DM + k0, Bs + row * 64 + lc * 8);
    }
    __syncthreads();
    #pragma unroll
    for (int kk = 0; kk < 2; ++kk) {
      bf16x8 af[4], bfr[4];
      #pragma unroll
      for (int i = 0; i < 4; ++i)
        af[i] = *(const bf16x8*)(As + (wr + i * 16 + m16) * 64 + ((kk * 4 + quad) ^ xr) * 8);
      #pragma unroll
      for (int j = 0; j < 4; ++j)
        bfr[j] = *(const bf16x8*)(Bs + (wc + j * 16 + m16) * 64 + ((kk * 4 + quad) ^ xr) * 8);
      #pragma unroll
      for (int i = 0; i < 4; ++i)
        #pragma unroll
        for (int j = 0; j < 4; ++j)
          acc[i][j] = __builtin_amdgcn_mfma_f32_16x16x32_bf16(af[i], bfr[j], acc[i][j], 0, 0, 0);
    }
    __syncthreads();
  }
}

// ---------------- GEMM1: qkv = xb @ Wt^T, scatter Q,K (bhsd) and V^T (bhds) ----------------
__global__ __launch_bounds__(256) void k_gemm_qkv(const unsigned short* __restrict__ xb,
                                                  const unsigned short* __restrict__ Bw,
                                                  unsigned short* __restrict__ Qb,
                                                  unsigned short* __restrict__ Kb,
                                                  unsigned short* __restrict__ Vt) {
  __shared__ __align__(16) unsigned short smem[18432];
  f32x4 acc[4][4] = {};
  int bn = blockIdx.x, bm = blockIdx.y;
  gemm_core_async(xb, Bw, bm, bn, smem, acc);

  int t = threadIdx.x, lane = t & 63, w = t >> 6;
  int m16 = lane & 15, quad = lane >> 4;
  int wr = (w >> 1) * 64, wc = (w & 1) * 64;
  int b = bm >> 4, srow = (bm & 15) * 128;
  int which = bn >> 3;
  ushort_t (*Tr)[130] = (ushort_t(*)[130])smem;
  if (which < 2) {
    #pragma unroll
    for (int i = 0; i < 4; ++i)
      #pragma unroll
      for (int j = 0; j < 4; ++j)
        #pragma unroll
        for (int r = 0; r < 4; ++r)
          Tr[wr + i * 16 + quad * 4 + r][wc + j * 16 + m16] = bf16b(acc[i][j][r]);
    __syncthreads();
    int row = t >> 1, half = t & 1;
    int cloc = bn * 128 + half * 64 - which * 1024;
    int h = cloc >> 6;
    unsigned short* dst = (which ? Kb : Qb) +
        ((size_t)(b * 16 + h) * 2048 + srow + row) * 64;
    #pragma unroll
    for (int p = 0; p < 8; ++p)
      *(uint4*)(dst + p * 8) = *(const uint4*)(&Tr[row][half * 64 + p * 8]);
  } else {
    #pragma unroll
    for (int i = 0; i < 4; ++i)
      #pragma unroll
      for (int j = 0; j < 4; ++j)
        #pragma unroll
        for (int r = 0; r < 4; ++r)
          Tr[wc + j * 16 + m16][wr + i * 16 + quad * 4 + r] = bf16b(acc[i][j][r]);
    __syncthreads();
    int dl = t >> 1, half = t & 1;
    int cloc = (bn - 16) * 128 + dl;
    int h = cloc >> 6, d = cloc & 63;
    unsigned short* dst = Vt + ((size_t)(b * 16 + h) * 64 + d) * 2048 + srow + half * 64;
    #pragma unroll
    for (int p = 0; p < 8; ++p)
      *(uint4*)(dst + p * 8) = *(const uint4*)(&Tr[dl][half * 64 + p * 8]);
  }
}

// ---------------- flash attention v4: 8 waves x 16q, K LDS dbuf, V in regs ----------------
// grid 512 x 512 threads: xcd = bid&7, jj = bid>>3, bh = (jj&3)*8+xcd, qtile = jj>>2.
// K staged via glds16 into double buffer (8 KB/tile); V loaded per-wave straight to
// registers from L2 (off the LDS pipe); P bounced through per-wave LDS; 1 barrier/iter.
// LDS: K dbuf 2*64*64 + P 8*16*68 = 16896 shorts = 33792 B -> 2 blocks/CU, 16 waves/CU.
__global__ __launch_bounds__(512, 2) void k_attn(const unsigned short* __restrict__ Qb,
                                                 const unsigned short* __restrict__ Kb,
                                                 const unsigned short* __restrict__ Vt,
                                                 unsigned short* __restrict__ AO) {
  __shared__ __align__(16) unsigned short smem[16896];
  int t = threadIdx.x;
  int w = t >> 6, lane = t & 63;
  int m16 = lane & 15, quad = lane >> 4;
  int bid = blockIdx.x;
  int jj = bid >> 3;
  int bh = ((jj & 3) << 3) + (bid & 7);
  int qbase = (jj >> 2) * 128 + w * 16;

  const unsigned short* Qp = Qb + ((size_t)bh * S_LEN + qbase + m16) * DH + quad * 8;
  bf16x8 aq0 = *(const bf16x8*)(Qp);
  bf16x8 aq1 = *(const bf16x8*)(Qp + 32);
  const unsigned short* Kbase = Kb + (size_t)bh * S_LEN * DH;
  const unsigned short* Vbase = Vt + (size_t)bh * DH * S_LEN;

  unsigned short* Pw = smem + 8192 + w * 1088;   // 16 x 68
  int xr = m16 & 7;

  // K staging: 512 threads, one 16B chunk each per tile
  int trow = t >> 3;            // 0..63
  int tcol = t & 7;
  int gswz = tcol ^ (trow & 7);

  f32x4 o[4] = {};
  float l = 0.f;
  f32x4 zero = {0.f, 0.f, 0.f, 0.f};

  glds16(Kbase + (size_t)trow * 64 + gswz * 8, smem + trow * 64 + tcol * 8);
  __syncthreads();

  #pragma unroll 1
  for (int kt = 0; kt < S_LEN / 64; ++kt) {
    int cur = kt & 1, nxt = cur ^ 1;
    int k0 = kt * 64;
    // V first half (keys k0..k0+31) -> regs; consumed ~1k cycles later in PV
    bf16x8 vfA[4];
    #pragma unroll
    for (int j = 0; j < 4; ++j)
      vfA[j] = *(const bf16x8*)(Vbase + (size_t)(j * 16 + m16) * S_LEN + k0 + quad * 8);
    // stage next K tile
    if (kt + 1 < S_LEN / 64) {
      glds16(Kbase + (size_t)(k0 + 64 + trow) * 64 + gswz * 8,
             smem + nxt * 4096 + trow * 64 + tcol * 8);
    }
    unsigned short* Ksh = smem + cur * 4096;

    // QK^T transposed: st[g] rows = keys g*16+quad*4+r, col = q-row m16
    f32x4 st[4];
    #pragma unroll
    for (int g = 0; g < 4; ++g) {
      int rk = g * 16 + m16;
      bf16x8 kf0 = *(const bf16x8*)(Ksh + rk * 64 + ((quad ^ xr) * 8));
      bf16x8 kf1 = *(const bf16x8*)(Ksh + rk * 64 + (((4 + quad) ^ xr) * 8));
      st[g] = __builtin_amdgcn_mfma_f32_16x16x32_bf16(kf0, aq0, zero, 0, 0, 0);
      st[g] = __builtin_amdgcn_mfma_f32_16x16x32_bf16(kf1, aq1, st[g], 0, 0, 0);
    }
    // V second half (keys k0+32..k0+63) -> regs; covered by softmax below
    bf16x8 vfB[4];
    #pragma unroll
    for (int j = 0; j < 4; ++j)
      vfB[j] = *(const bf16x8*)(Vbase + (size_t)(j * 16 + m16) * S_LEN + k0 + 32 + quad * 8);
    // softmax: p = 2^s (log2e folded into Wq; no max needed)
    #pragma unroll
    for (int g = 0; g < 4; ++g) {
      float p0 = exp2v(st[g][0]), p1 = exp2v(st[g][1]);
      float p2 = exp2v(st[g][2]), p3 = exp2v(st[g][3]);
      l += (p0 + p1) + (p2 + p3);
      uint2 pk;
      pk.x = ((unsigned)bf16b(p1) << 16) | bf16b(p0);
      pk.y = ((unsigned)bf16b(p3) << 16) | bf16b(p2);
      *(uint2*)(Pw + m16 * 68 + g * 16 + quad * 4) = pk;
    }
    // PV: o(16q x 64d) += P(16x64) @ V^T(64keys x 64d), V from registers
    {
      bf16x8 ap0 = *(const bf16x8*)(Pw + m16 * 68 + quad * 8);
      bf16x8 ap1 = *(const bf16x8*)(Pw + m16 * 68 + 32 + quad * 8);
      #pragma unroll
      for (int j = 0; j < 4; ++j) {
        o[j] = __builtin_amdgcn_mfma_f32_16x16x32_bf16(ap0, vfA[j], o[j], 0, 0, 0);
        o[j] = __builtin_amdgcn_mfma_f32_16x16x32_bf16(ap1, vfB[j], o[j], 0, 0, 0);
      }
    }
    __syncthreads();   // K buf[cur] reads done; buf[nxt] staging drained
  }

  l += __shfl_xor(l, 16); l += __shfl_xor(l, 32);
  float iv = 1.0f / l;
  int b = bh >> 4, h = bh & 15;
  #pragma unroll
  for (int r = 0; r < 4; ++r) {
    float v0 = __shfl(iv, quad * 4 + r);
    size_t row0 = (size_t)b * S_LEN + qbase + quad * 4 + r;
    unsigned short* d0 = AO + row0 * DM + h * DH + m16;
    #pragma unroll
    for (int j = 0; j < 4; ++j)
      d0[j * 16] = bf16b(o[j][r] * v0);
  }
}

// ---------------- GEMM2: out = AO @ Wot^T + bias (fp32 out), grid (8, 32) ----------------
__global__ __launch_bounds__(256) void k_gemm_out(const unsigned short* __restrict__ A,
                                                  const unsigned short* __restrict__ Bw,
                                                  const float* __restrict__ bias,
                                                  float* __restrict__ out) {
  __shared__ __align__(16) unsigned short smem[18432];
  f32x4 acc[4][4] = {};
  int bn = blockIdx.x, bm = blockIdx.y;
  gemm_core_async(A, Bw, bm, bn, smem, acc);

  int t = threadIdx.x, lane = t & 63, w = t >> 6;
  int m16 = lane & 15, quad = lane >> 4;
  int wr = (w >> 1) * 64, wc = (w & 1) * 64;
  #pragma unroll
  for (int i = 0; i < 4; ++i) {
    int grow = bm * 128 + wr + i * 16 + quad * 4;
    #pragma unroll
    for (int j = 0; j < 4; ++j) {
      int gc = bn * 128 + wc + j * 16 + m16;
      float bb = bias[gc];
      #pragma unroll
      for (int r = 0; r < 4; ++r)
        out[(size_t)(grow + r) * DM + gc] = acc[i][j][r] + bb;
    }
  }
}

extern "C" void kernel_launch(void* const* d_in, const int* in_sizes, int n_in,
                              void* d_out, int out_size, void* d_ws, size_t ws_size,
                              hipStream_t stream) {
  const float* x    = (const float*)d_in[0];
  const float* wqkv = (const float*)d_in[1];
  const float* wout = (const float*)d_in[2];
  const float* bout = (const float*)d_in[3];
  const float* mlog = (const float*)d_in[4];
  char* ws = (char*)d_ws;
  unsigned short* Wt  = (unsigned short*)(ws + OFF_WT);
  unsigned short* Wot = (unsigned short*)(ws + OFF_WOT);
  unsigned short* Qb  = (unsigned short*)(ws + OFF_Q);
  unsigned short* Kb  = (unsigned short*)(ws + OFF_K);
  unsigned short* Vt  = (unsigned short*)(ws + OFF_V);
  unsigned short* xb  = (unsigned short*)(ws + OFF_AO);
  unsigned short* AO  = (unsigned short*)(ws + OFF_AO);
  float* out = (float*)d_out;

  k_prep<<<dim3(2816), dim3(256), 0, stream>>>(wqkv, wout, x, mlog, Wt, Wot, xb);
  k_gemm_qkv<<<dim3(24, 32), dim3(256), 0, stream>>>(xb, Wt, Qb, Kb, Vt);
  k_attn<<<dim3(512), dim3(512), 0, stream>>>(Qb, Kb, Vt, AO);
  k_gemm_out<<<dim3(8, 32), dim3(256), 0, stream>>>(AO, Wot, bout, out);
}